// Round 1
// 3926.685 us; speedup vs baseline: 2.4905x; 2.4905x over previous
//
#include <hip/hip_runtime.h>

// Problem constants (GPT forward):
#define VV     50257
#define DMODEL 384
#define NH     6
#define HSZ    64
#define NL     6
#define TSEQ   256
#define BBAT   8
#define MROWS  (BBAT*TSEQ)   // 2048
#define LNEPS  1e-5f

// emb[t,j]: j even -> sin(t*div[j/2]); j odd -> cos(t*div[(j-1)/2])
__device__ __forceinline__ float rope_emb(int t, int j) {
    int m = j >> 1;
    float div = expf((2.0f * (float)m) * (-logf(10000.0f) / 64.0f));
    float ang = (float)t * div;
    return (j & 1) ? cosf(ang) : sinf(ang);
}

// ---------------- embedding gather ----------------
__global__ void embed_kernel(const int* __restrict__ idx, const float* __restrict__ tok,
                             float* __restrict__ x) {
    int i = blockIdx.x * blockDim.x + threadIdx.x;
    if (i < MROWS * DMODEL) {
        int row = i / DMODEL, col = i % DMODEL;
        x[i] = tok[(size_t)idx[row] * DMODEL + col];
    }
}

// ---------------- layernorm (one block per row, 384 threads) ----------------
__global__ void ln_kernel(const float* __restrict__ x, const float* __restrict__ g,
                          const float* __restrict__ b, float* __restrict__ out) {
    int row = blockIdx.x;
    int j = threadIdx.x;               // 0..383
    float v = x[row * DMODEL + j];
    float sum = v, sq = v * v;
    __shared__ float s_sum[6], s_sq[6];
    int wave = j >> 6, lane = j & 63;
    #pragma unroll
    for (int off = 32; off; off >>= 1) {
        sum += __shfl_down(sum, off);
        sq  += __shfl_down(sq, off);
    }
    if (lane == 0) { s_sum[wave] = sum; s_sq[wave] = sq; }
    __syncthreads();
    if (j == 0) {
        float ts = 0.f, tq = 0.f;
        #pragma unroll
        for (int w = 0; w < 6; w++) { ts += s_sum[w]; tq += s_sq[w]; }
        float mu = ts / (float)DMODEL;
        float var = tq / (float)DMODEL - mu * mu;
        s_sum[0] = mu;
        s_sq[0] = rsqrtf(var + LNEPS);
    }
    __syncthreads();
    float mu = s_sum[0], r = s_sq[0];
    out[row * DMODEL + j] = (v - mu) * r * g[j] + b[j];
}

// ---------------- repack Wq/Wk/Wv (H,D,HS each) -> wr (D, 3*D) for fused QKV GEMM ----
__global__ void repack_qkv(const float* __restrict__ Wq, const float* __restrict__ Wk,
                           const float* __restrict__ Wv, float* __restrict__ wr) {
    int i = blockIdx.x * 256 + threadIdx.x;     // < 384*1152
    int d = i / (3 * DMODEL);
    int n = i % (3 * DMODEL);
    int which = n / DMODEL;
    int hj = n % DMODEL;
    const float* src = (which == 0) ? Wq : (which == 1) ? Wk : Wv;
    wr[i] = src[((size_t)((hj >> 6) * DMODEL + d)) * HSZ + (hj & 63)];
}

// ---------------- gemm64: 64x64 tile, BK=16, 4x4 micro, conflict-free lane remap ----
// Requires: M%64==0, N%64==0, N%4==0, K%16==0, K%4==0.
template<bool RELU, bool RES, bool BIAS>
__launch_bounds__(256)
__global__ void gemm64_kernel(const float* __restrict__ A, const float* __restrict__ W,
                              const float* __restrict__ bias, const float* __restrict__ res,
                              float* __restrict__ outp, int Mdim, int Ndim, int Kdim) {
    __shared__ float As[16][68];   // transposed A tile, pitch 68 (bank spread)
    __shared__ float Bs[16][64];
    int tid = threadIdx.x;
    int lane = tid & 63, wid = tid >> 6;
    // wave covers 8x8 (tx,ty): 8 distinct LDS addrs per read -> banks 0..31 once each
    int tx = (lane & 7) + (wid & 1) * 8;       // 0..15
    int ty = (lane >> 3) + (wid >> 1) * 8;     // 0..15
    int row0 = blockIdx.x * 64;
    int col0 = blockIdx.y * 64;

    int ar_ = tid >> 2, ac4 = tid & 3;         // A staging: row, k-quad
    int br_ = tid >> 4, bc4 = tid & 15;        // B staging: k-row, col-quad
    const float* Aptr = A + (size_t)(row0 + ar_) * Kdim + ac4 * 4;
    const float* Wptr = W + (size_t)br_ * Ndim + col0 + bc4 * 4;

    float acc[4][4] = {};
    for (int k0 = 0; k0 < Kdim; k0 += 16) {
        float4 av = *(const float4*)(Aptr + k0);
        float4 bv = *(const float4*)(Wptr + (size_t)k0 * Ndim);
        As[ac4 * 4 + 0][ar_] = av.x;
        As[ac4 * 4 + 1][ar_] = av.y;
        As[ac4 * 4 + 2][ar_] = av.z;
        As[ac4 * 4 + 3][ar_] = av.w;
        *(float4*)&Bs[br_][bc4 * 4] = bv;
        __syncthreads();
        #pragma unroll
        for (int kk = 0; kk < 16; kk++) {
            float4 a = *(const float4*)&As[kk][ty * 4];
            float4 b = *(const float4*)&Bs[kk][tx * 4];
            float aa[4] = {a.x, a.y, a.z, a.w};
            float bb[4] = {b.x, b.y, b.z, b.w};
            #pragma unroll
            for (int i = 0; i < 4; i++)
                #pragma unroll
                for (int j = 0; j < 4; j++) acc[i][j] += aa[i] * bb[j];
        }
        __syncthreads();
    }

    #pragma unroll
    for (int i = 0; i < 4; i++) {
        size_t base = (size_t)(row0 + ty * 4 + i) * Ndim + col0 + tx * 4;
        float4 o = make_float4(acc[i][0], acc[i][1], acc[i][2], acc[i][3]);
        if (BIAS) {
            float4 bv = *(const float4*)&bias[col0 + tx * 4];
            o.x += bv.x; o.y += bv.y; o.z += bv.z; o.w += bv.w;
        }
        if (RELU) {
            o.x = fmaxf(o.x, 0.f); o.y = fmaxf(o.y, 0.f);
            o.z = fmaxf(o.z, 0.f); o.w = fmaxf(o.w, 0.f);
        }
        if (RES) {
            float4 rv = *(const float4*)&res[base];
            o.x += rv.x; o.y += rv.y; o.z += rv.z; o.w += rv.w;
        }
        *(float4*)&outp[base] = o;
    }
}

// ---------------- gemm128: 128x128 tile, BK=16, 8x8 micro (for LM head, ragged N) ----
// Requires: M%128==0, K%16==0, K%4==0. N arbitrary (guarded scalar B/C path).
template<bool RELU, bool BIAS>
__launch_bounds__(256)
__global__ void gemm128_kernel(const float* __restrict__ A, const float* __restrict__ W,
                               const float* __restrict__ bias, float* __restrict__ outp,
                               int Mdim, int Ndim, int Kdim) {
    __shared__ float As[16][132];  // transposed A tile; pitch 132 (aligned + bank spread)
    __shared__ float Bs[16][128];
    int tid = threadIdx.x;
    int lane = tid & 63, wid = tid >> 6;
    int tx = (lane & 7) + (wid & 1) * 8;       // 0..15
    int ty = (lane >> 3) + (wid >> 1) * 8;     // 0..15
    int row0 = blockIdx.x * 128;
    int col0 = blockIdx.y * 128;

    int ar_ = tid >> 1;            // 0..127 (A row)
    int aq0 = (tid & 1) * 8;       // k-offset 0 or 8 (two float4 each)
    const float* Aptr = A + (size_t)(row0 + ar_) * Kdim + aq0;

    float acc[8][8] = {};
    for (int k0 = 0; k0 < Kdim; k0 += 16) {
        float4 a0 = *(const float4*)(Aptr + k0);
        float4 a1 = *(const float4*)(Aptr + k0 + 4);
        As[aq0 + 0][ar_] = a0.x; As[aq0 + 1][ar_] = a0.y;
        As[aq0 + 2][ar_] = a0.z; As[aq0 + 3][ar_] = a0.w;
        As[aq0 + 4][ar_] = a1.x; As[aq0 + 5][ar_] = a1.y;
        As[aq0 + 6][ar_] = a1.z; As[aq0 + 7][ar_] = a1.w;
        #pragma unroll
        for (int i = tid; i < 2048; i += 256) {        // B: 16x128, guarded scalar loads
            int r = i >> 7, cc = i & 127;
            int gc = col0 + cc;
            Bs[r][cc] = (gc < Ndim) ? W[(size_t)(k0 + r) * Ndim + gc] : 0.f;
        }
        __syncthreads();
        #pragma unroll
        for (int kk = 0; kk < 16; kk++) {
            float4 a0v = *(const float4*)&As[kk][ty * 8];
            float4 a1v = *(const float4*)&As[kk][ty * 8 + 4];
            float4 b0v = *(const float4*)&Bs[kk][tx * 8];
            float4 b1v = *(const float4*)&Bs[kk][tx * 8 + 4];
            float aa[8] = {a0v.x, a0v.y, a0v.z, a0v.w, a1v.x, a1v.y, a1v.z, a1v.w};
            float bb[8] = {b0v.x, b0v.y, b0v.z, b0v.w, b1v.x, b1v.y, b1v.z, b1v.w};
            #pragma unroll
            for (int i = 0; i < 8; i++)
                #pragma unroll
                for (int j = 0; j < 8; j++) acc[i][j] += aa[i] * bb[j];
        }
        __syncthreads();
    }

    #pragma unroll
    for (int i = 0; i < 8; i++) {
        int gr = row0 + ty * 8 + i;
        #pragma unroll
        for (int j = 0; j < 8; j++) {
            int gc = col0 + tx * 8 + j;
            if (gc < Ndim) {
                float o = acc[i][j];
                if (BIAS) o += bias[gc];
                if (RELU) o = fmaxf(o, 0.f);
                outp[(size_t)gr * Ndim + gc] = o;
            }
        }
    }
}

// ---------------- causal attention, online softmax, LDS-tiled K/V, RoPE fused ------
// grid (B*H, T/64); 256 threads = 64 queries x 4 dim-quads (16 dims each).
__launch_bounds__(256)
__global__ void attn_kernel(const float* __restrict__ qkv, float* __restrict__ att) {
    int bh = blockIdx.x;            // 0..47
    int qt = blockIdx.y;            // 0..3
    int b = bh / NH, h = bh % NH;
    int tid = threadIdx.x;
    int ql = tid >> 2;              // query within tile, 0..63
    int quad = tid & 3;             // dim quarter
    int t = qt * 64 + ql;

    __shared__ float Ks[64][64];
    __shared__ float Vs[64][64];

    // Q load + RoPE (this thread's 16 dims: [quad*16, quad*16+16))
    float qreg[16];
    const float* qr = qkv + (size_t)(b * TSEQ + t) * (3 * DMODEL) + h * HSZ;
    #pragma unroll
    for (int u = 0; u < 8; u++) {
        int p = quad * 8 + u;       // pair index 0..31
        float q0 = qr[2 * p], q1 = qr[2 * p + 1];
        qreg[2 * u]     = -q1 * rope_emb(t, 32 + p);
        qreg[2 * u + 1] =  q0 * rope_emb(t, p);
    }

    float m = -1e30f, l = 0.f;
    float acc[16];
    #pragma unroll
    for (int i = 0; i < 16; i++) acc[i] = 0.f;
    const float scale = 0.125f;

    for (int tile = 0; tile <= qt; tile++) {
        int s0 = tile * 64;
        __syncthreads();
        // stage K with RoPE: 64x64 floats as 2048 float2
        for (int i = tid; i < 2048; i += 256) {
            int s = i >> 5, p = i & 31;
            const float* kr = qkv + (size_t)(b * TSEQ + s0 + s) * (3 * DMODEL)
                              + DMODEL + h * HSZ + 2 * p;
            float k0 = kr[0], k1 = kr[1];
            Ks[s][2 * p]     = -k1 * rope_emb(s0 + s, 32 + p);
            Ks[s][2 * p + 1] =  k0 * rope_emb(s0 + s, p);
        }
        // stage V: 64x64 floats as 1024 float4
        for (int i = tid; i < 1024; i += 256) {
            int s = i >> 4, c = (i & 15) * 4;
            const float* vr = qkv + (size_t)(b * TSEQ + s0 + s) * (3 * DMODEL)
                              + 2 * DMODEL + h * HSZ + c;
            *(float4*)&Vs[s][c] = *(const float4*)vr;
        }
        __syncthreads();
        for (int s = 0; s < 64; s++) {
            int gs = s0 + s;
            const float4* kk4 = (const float4*)&Ks[s][quad * 16];
            float4 ka = kk4[0], kb = kk4[1], kc = kk4[2], kd = kk4[3];
            float w0 = qreg[0] * ka.x + qreg[4] * kb.x + qreg[8]  * kc.x + qreg[12] * kd.x;
            float w1 = qreg[1] * ka.y + qreg[5] * kb.y + qreg[9]  * kc.y + qreg[13] * kd.y;
            float w2 = qreg[2] * ka.z + qreg[6] * kb.z + qreg[10] * kc.z + qreg[14] * kd.z;
            float w3 = qreg[3] * ka.w + qreg[7] * kb.w + qreg[11] * kc.w + qreg[15] * kd.w;
            float w = (w0 + w1) + (w2 + w3);
            w += __shfl_xor(w, 1);
            w += __shfl_xor(w, 2);     // all 4 quad-lanes now hold the full dot
            w *= scale;
            if (gs > t) w = -1e30f;    // causal mask (s=0 always valid, so m stays sane)
            float mn = fmaxf(m, w);
            float corr = expf(m - mn);
            float p = expf(w - mn);
            l = l * corr + p;
            const float4* vv4 = (const float4*)&Vs[s][quad * 16];
            float4 va = vv4[0], vb = vv4[1], vc = vv4[2], vd = vv4[3];
            acc[0]  = acc[0]  * corr + p * va.x;  acc[1]  = acc[1]  * corr + p * va.y;
            acc[2]  = acc[2]  * corr + p * va.z;  acc[3]  = acc[3]  * corr + p * va.w;
            acc[4]  = acc[4]  * corr + p * vb.x;  acc[5]  = acc[5]  * corr + p * vb.y;
            acc[6]  = acc[6]  * corr + p * vb.z;  acc[7]  = acc[7]  * corr + p * vb.w;
            acc[8]  = acc[8]  * corr + p * vc.x;  acc[9]  = acc[9]  * corr + p * vc.y;
            acc[10] = acc[10] * corr + p * vc.z;  acc[11] = acc[11] * corr + p * vc.w;
            acc[12] = acc[12] * corr + p * vd.x;  acc[13] = acc[13] * corr + p * vd.y;
            acc[14] = acc[14] * corr + p * vd.z;  acc[15] = acc[15] * corr + p * vd.w;
            m = mn;
        }
    }
    float inv = 1.f / l;
    float* ar = att + ((size_t)(b * TSEQ + t) * NH + h) * HSZ + quad * 16;
    #pragma unroll
    for (int i = 0; i < 16; i++) ar[i] = acc[i] * inv;
}

extern "C" void kernel_launch(void* const* d_in, const int* in_sizes, int n_in,
                              void* d_out, int out_size, void* d_ws, size_t ws_size,
                              hipStream_t stream) {
    const int*   idx  = (const int*)d_in[0];
    const float* tok  = (const float*)d_in[1];
    const float* Wq   = (const float*)d_in[2];
    const float* Wk   = (const float*)d_in[3];
    const float* Wv   = (const float*)d_in[4];
    const float* Wp   = (const float*)d_in[5];
    const float* bp   = (const float*)d_in[6];
    const float* W1   = (const float*)d_in[7];
    const float* b1   = (const float*)d_in[8];
    const float* W2   = (const float*)d_in[9];
    const float* b2   = (const float*)d_in[10];
    const float* ln1g = (const float*)d_in[11];
    const float* ln1b = (const float*)d_in[12];
    const float* ln2g = (const float*)d_in[13];
    const float* ln2b = (const float*)d_in[14];
    const float* lnfg = (const float*)d_in[15];
    const float* lnfb = (const float*)d_in[16];
    const float* lmW  = (const float*)d_in[17];
    const float* lmb  = (const float*)d_in[18];
    float* out = (float*)d_out;

    const int ND = MROWS * DMODEL;       // 786432
    float* x    = (float*)d_ws;
    float* xn   = x    + ND;
    float* qkvb = xn   + ND;             // MROWS * 1152
    float* att  = qkvb + MROWS * 3 * DMODEL;
    float* h1   = att  + ND;             // MROWS * 1536
    float* wr   = h1;                    // alias: wr used (repack+qkv GEMM) strictly
                                         // before fc1 writes h1 each layer

    embed_kernel<<<(ND + 255) / 256, 256, 0, stream>>>(idx, tok, x);

    for (int l = 0; l < NL; l++) {
        ln_kernel<<<MROWS, DMODEL, 0, stream>>>(x, ln1g + l * DMODEL, ln1b + l * DMODEL, xn);
        repack_qkv<<<(DMODEL * 3 * DMODEL) / 256, 256, 0, stream>>>(
            Wq + (size_t)l * NH * DMODEL * HSZ, Wk + (size_t)l * NH * DMODEL * HSZ,
            Wv + (size_t)l * NH * DMODEL * HSZ, wr);
        gemm64_kernel<false, false, false><<<dim3(MROWS / 64, 3 * DMODEL / 64), 256, 0, stream>>>(
            xn, wr, nullptr, nullptr, qkvb, MROWS, 3 * DMODEL, DMODEL);
        attn_kernel<<<dim3(BBAT * NH, TSEQ / 64), 256, 0, stream>>>(qkvb, att);
        gemm64_kernel<false, true, true><<<dim3(MROWS / 64, DMODEL / 64), 256, 0, stream>>>(
            att, Wp + (size_t)l * DMODEL * DMODEL, bp + l * DMODEL, x, x,
            MROWS, DMODEL, DMODEL);
        ln_kernel<<<MROWS, DMODEL, 0, stream>>>(x, ln2g + l * DMODEL, ln2b + l * DMODEL, xn);
        gemm64_kernel<true, false, true><<<dim3(MROWS / 64, 4 * DMODEL / 64), 256, 0, stream>>>(
            xn, W1 + (size_t)l * DMODEL * 4 * DMODEL, b1 + l * 4 * DMODEL, nullptr, h1,
            MROWS, 4 * DMODEL, DMODEL);
        gemm64_kernel<false, true, true><<<dim3(MROWS / 64, DMODEL / 64), 256, 0, stream>>>(
            h1, W2 + (size_t)l * 4 * DMODEL * DMODEL, b2 + l * DMODEL, x, x,
            MROWS, DMODEL, 4 * DMODEL);
    }

    ln_kernel<<<MROWS, DMODEL, 0, stream>>>(x, lnfg, lnfb, xn);
    // row-tile-major grid: consecutive blocks share the same W col-tile (L2-hot)
    gemm128_kernel<false, true><<<dim3(MROWS / 128, (VV + 127) / 128), 256, 0, stream>>>(
        xn, lmW, lmb, out, MROWS, VV, DMODEL);
}